// Round 1
// baseline (17105.791 us; speedup 1.0000x reference)
//
#include <hip/hip_runtime.h>
#include <stdint.h>

#define TT 512
#define BB 64
#define II 512
#define HH 1024

typedef __attribute__((ext_vector_type(8))) _Float16 half8;
typedef __attribute__((ext_vector_type(4))) float f32x4;

__device__ __forceinline__ float fsig(float x)  { return 1.0f / (1.0f + __expf(-x)); }
__device__ __forceinline__ float ftanh(float x) { return 1.0f - 2.0f / (1.0f + __expf(2.0f * x)); }

// ws layout: [0,1KB) flags[4][64], [4096, 4096+256KB) z: 4 chains x dbuf x [16][1024] fp16
#define WS_Z_OFF 4096
#define WS_BYTES (WS_Z_OFF + 4 * 2 * 16 * HH * 2)

// Zero flags AND all z buffers (h0 = 0) up front; kernel-boundary ordering on the
// stream makes these visible to the persist kernel's L3-scope atomics.
__global__ void lstm_init(uint32_t* ws) {
  const uint32_t i = blockIdx.x * 256u + threadIdx.x;
  if (i < WS_BYTES / 4) ws[i] = 0u;
}

// Persistent LSTM: 64 WGs = 64 col-groups (16 h-cols x 4 gates each).
// Each WG serves ALL 4 independent batch-group chains per timestep, reusing the same
// VGPR-resident weight fragments. Chain interleave hides the L3 publish->poll RTT:
// chain c's sync latency is covered by chains c+1..c+3's compute.
__global__ __launch_bounds__(256, 1)
void lstm_persist(const float* __restrict__ x,
                  const float* __restrict__ wii, const float* __restrict__ bii,
                  const float* __restrict__ wif_, const float* __restrict__ bif_,
                  const float* __restrict__ wig, const float* __restrict__ big_,
                  const float* __restrict__ wio, const float* __restrict__ bio,
                  const float* __restrict__ whi, const float* __restrict__ bhi,
                  const float* __restrict__ whf, const float* __restrict__ bhf,
                  const float* __restrict__ whg, const float* __restrict__ bhg,
                  const float* __restrict__ who, const float* __restrict__ bho,
                  float* __restrict__ out, uint8_t* __restrict__ ws)
{
  const int tid  = threadIdx.x;
  const int wid  = tid >> 6;      // wave 0..3 : K-split (K = 1536 = 512 x + 1024 h)
  const int lane = tid & 63;
  const int quad = lane >> 4;
  const int lrow = lane & 15;

  const int gc   = blockIdx.x;    // col group 0..63
  const int col0 = gc << 4;

  const float* wi[4] = {wii, wif_, wig, wio};
  const float* wh[4] = {whi, whf, whg, who};
  const float* bi[4] = {bii, bif_, big_, bio};
  const float* bh[4] = {bhi, bhf, bhg, bho};

  uint32_t* flagbase = (uint32_t*)ws;
  _Float16* zall     = (_Float16*)(ws + WS_Z_OFF);

  // ---- persistent weight fragments (B operand: B[k][n], n=lane&15, k=quad*8+j) ----
  const int kb = wid * 384;       // this wave's K-range in concatenated K=[x(512); h(1024)]
  half8 wfrag[12][4];
#pragma unroll
  for (int kk = 0; kk < 12; ++kk) {
    const int k = kb + kk * 32 + quad * 8;
#pragma unroll
    for (int g = 0; g < 4; ++g) {
      const float* wp = (k < II) ? (wi[g] + (size_t)(col0 + lrow) * II + k)
                                 : (wh[g] + (size_t)(col0 + lrow) * HH + (k - II));
      half8 v;
#pragma unroll
      for (int j = 0; j < 8; ++j) v[j] = (_Float16)wp[j];
      wfrag[kk][g] = v;
    }
  }

  // per-thread elementwise ownership: (tb, thc) = one (batch-in-group, h-col) cell
  const int tb   = tid >> 4;
  const int thc  = tid & 15;
  const int gcol = col0 + thc;
  float bias[4];
#pragma unroll
  for (int g = 0; g < 4; ++g) bias[g] = bi[g][gcol] + bh[g][gcol];

  float cst[4] = {0.f, 0.f, 0.f, 0.f};
  float hst[4] = {0.f, 0.f, 0.f, 0.f};

  __shared__ float red[16 * 288];  // quad stride 72 -> max 2-way bank alias (free)
  __shared__ __attribute__((aligned(16))) _Float16 hstage[4][256];

  auto poll = [&](uint32_t* flags, uint32_t target) {
    int guard = 0;
    for (;;) {
      uint32_t v = __hip_atomic_load(&flags[lane], __ATOMIC_RELAXED, __HIP_MEMORY_SCOPE_AGENT);
      if (__ballot((int)(v >= target)) == ~0ull) break;
      __builtin_amdgcn_s_sleep(1);
      if (++guard > (1 << 19)) break;   // fail loud, not hang
    }
  };

#pragma unroll 1
  for (int t = 0; t < TT; ++t) {
#pragma unroll 1
    for (int c = 0; c < 4; ++c) {
      uint32_t* flags     = flagbase + (c << 6);
      _Float16* zc        = zall + c * (2 * 16 * HH);
      const _Float16* zp  = zc + (t & 1) * (16 * HH);
      _Float16*       zn  = zc + ((t + 1) & 1) * (16 * HH);
      const float* xrow   = x + ((size_t)t * BB + (c << 4) + lrow) * II;
      const _Float16* zrow = zp + lrow * HH;

      half8 af[12];
      // x-part A frags (independent of h) -- issue BEFORE the poll so they fly
      // during the wait. A[m=lane&15][k=quad*8+j].
#pragma unroll
      for (int kk = 0; kk < 12; ++kk) {
        const int k = kb + kk * 32 + quad * 8;
        if (kb + kk * 32 < II) {
          f32x4 v0 = *(const f32x4*)(xrow + k);
          f32x4 v1 = *(const f32x4*)(xrow + k + 4);
          half8 v;
#pragma unroll
          for (int j = 0; j < 4; ++j) { v[j] = (_Float16)v0[j]; v[4 + j] = (_Float16)v1[j]; }
          af[kk] = v;
        }
      }

      // wait until every WG has published h_t for this chain (waves with h-K only)
      if (wid > 0 && t > 0) poll(flags, (uint32_t)t);

      // h-part A frags via L3-scope atomics (bypass stale L2)
#pragma unroll
      for (int kk = 0; kk < 12; ++kk) {
        const int k = kb + kk * 32 + quad * 8;
        if (kb + kk * 32 >= II) {
          const uint64_t* p = (const uint64_t*)(zrow + (k - II));
          union { uint64_t u[2]; half8 v; } cv;
          cv.u[0] = __hip_atomic_load(p,     __ATOMIC_RELAXED, __HIP_MEMORY_SCOPE_AGENT);
          cv.u[1] = __hip_atomic_load(p + 1, __ATOMIC_RELAXED, __HIP_MEMORY_SCOPE_AGENT);
          af[kk] = cv.v;
        }
      }

      f32x4 acc[4];
#pragma unroll
      for (int g = 0; g < 4; ++g) acc[g] = (f32x4){0.f, 0.f, 0.f, 0.f};
#pragma unroll
      for (int kk = 0; kk < 12; ++kk)
#pragma unroll
        for (int g = 0; g < 4; ++g)
          acc[g] = __builtin_amdgcn_mfma_f32_16x16x32_f16(af[kk], wfrag[kk][g], acc[g], 0, 0, 0);

      // cross-wave K reduction via LDS; D layout: row(m)=quad*4+r, col(n)=lane&15
#pragma unroll
      for (int g = 0; g < 4; ++g)
#pragma unroll
        for (int r = 0; r < 4; ++r)
          red[(wid * 4 + g) * 288 + quad * 72 + r * 16 + lrow] = acc[g][r];
      __syncthreads();

      float pre[4];
#pragma unroll
      for (int g = 0; g < 4; ++g) {
        float s = bias[g];
#pragma unroll
        for (int w = 0; w < 4; ++w)
          s += red[(w * 4 + g) * 288 + (tb >> 2) * 72 + (tb & 3) * 16 + thc];
        pre[g] = s;
      }

      const float it = fsig(pre[0]);
      const float ft = fsig(pre[1]);
      const float gt = ftanh(pre[2]);
      const float ot = fsig(pre[3]);
      cst[c] = ft * cst[c] + it * gt;
      hst[c] = ot * ftanh(cst[c]);

      hstage[c][tb * 16 + thc] = (_Float16)hst[c];          // LDS stage for coalesced publish
      out[((size_t)t * BB + (c << 4) + tb) * HH + gcol] = hst[c];

      __syncthreads();   // hstage[c] complete; red consumed; all waves done reading zp

      // publish rotates across waves: wave c publishes chain c, then rejoins late
      // while the other 3 waves already run chain c+1 -> ack latency hidden.
      if (wid == c && t < TT - 1) {
        const int row = lane >> 2, c4 = (lane & 3) * 4;
        const uint64_t val = *(const uint64_t*)&hstage[c][row * 16 + c4];
        __hip_atomic_store((uint64_t*)(zn + row * HH + col0 + c4), val,
                           __ATOMIC_RELAXED, __HIP_MEMORY_SCOPE_AGENT);
        asm volatile("s_waitcnt vmcnt(0)" ::: "memory");   // z stores acked at L3
        if (lane == 0)
          __hip_atomic_store(&flags[gc], (uint32_t)(t + 1),
                             __ATOMIC_RELAXED, __HIP_MEMORY_SCOPE_AGENT);
      }
    }
  }

  // tails: h_T then c_T, each [B][H]
#pragma unroll
  for (int c = 0; c < 4; ++c) {
    out[(size_t)TT * BB * HH + (size_t)((c << 4) + tb) * HH + gcol] = hst[c];
    out[(size_t)TT * BB * HH + (size_t)BB * HH + (size_t)((c << 4) + tb) * HH + gcol] = cst[c];
  }
}

extern "C" void kernel_launch(void* const* d_in, const int* in_sizes, int n_in,
                              void* d_out, int out_size, void* d_ws, size_t ws_size,
                              hipStream_t stream) {
  const float* x    = (const float*)d_in[0];
  const float* wii  = (const float*)d_in[1];
  const float* bii  = (const float*)d_in[2];
  const float* wif_ = (const float*)d_in[3];
  const float* bif_ = (const float*)d_in[4];
  const float* wig  = (const float*)d_in[5];
  const float* big_ = (const float*)d_in[6];
  const float* wio  = (const float*)d_in[7];
  const float* bio  = (const float*)d_in[8];
  const float* whi  = (const float*)d_in[9];
  const float* bhi  = (const float*)d_in[10];
  const float* whf  = (const float*)d_in[11];
  const float* bhf  = (const float*)d_in[12];
  const float* whg  = (const float*)d_in[13];
  const float* bhg  = (const float*)d_in[14];
  const float* who  = (const float*)d_in[15];
  const float* bho  = (const float*)d_in[16];

  lstm_init<<<(WS_BYTES / 4 + 255) / 256, 256, 0, stream>>>((uint32_t*)d_ws);
  lstm_persist<<<64, 256, 0, stream>>>(x, wii, bii, wif_, bif_, wig, big_, wio, bio,
                                       whi, bhi, whf, bhf, whg, bhg, who, bho,
                                       (float*)d_out, (uint8_t*)d_ws);
}

// Round 2
// 4705.876 us; speedup vs baseline: 3.6350x; 3.6350x over previous
//
#include <hip/hip_runtime.h>
#include <stdint.h>

#define TT 512
#define BB 64
#define II 512
#define HH 1024

typedef __attribute__((ext_vector_type(8))) _Float16 half8;
typedef __attribute__((ext_vector_type(4))) float f32x4;

__device__ __forceinline__ float fsig(float x)  { return 1.0f / (1.0f + __expf(-x)); }
__device__ __forceinline__ float ftanh(float x) { return 1.0f - 2.0f / (1.0f + __expf(2.0f * x)); }

// ws: 4 batch-groups x dbuf x [16][HH] f32 h words; low 3 bits of each word = step tag.
// tag(t) = 1 + (t & 3) in {1,2,3,4}; init 0 never matches; t vs t-2 tags always differ.
#define ZWORDS (4 * 2 * 16 * HH)

__global__ void lstm_init(uint32_t* ws) {
  const uint32_t i = blockIdx.x * 256u + threadIdx.x;
  if (i < ZWORDS) ws[i] = 0u;
}

// Persistent LSTM: 256 WGs = 4 batch-groups (16 batches) x 64 col-groups (16 h-cols x 4 gates).
// Weights live in VGPRs as fp16 MFMA B-frags. Cross-WG h exchange: SELF-VALIDATING tagged
// f32 words through L3 (relaxed agent atomics). No flags, no publisher acks, no drain
// barriers -- sync cost is a single one-way L3 latency, overlapped with x-loads.
__global__ __launch_bounds__(256, 1)
void lstm_persist(const float* __restrict__ x,
                  const float* __restrict__ wii, const float* __restrict__ bii,
                  const float* __restrict__ wif_, const float* __restrict__ bif_,
                  const float* __restrict__ wig, const float* __restrict__ big_,
                  const float* __restrict__ wio, const float* __restrict__ bio,
                  const float* __restrict__ whi, const float* __restrict__ bhi,
                  const float* __restrict__ whf, const float* __restrict__ bhf,
                  const float* __restrict__ whg, const float* __restrict__ bhg,
                  const float* __restrict__ who, const float* __restrict__ bho,
                  float* __restrict__ out, uint8_t* __restrict__ ws)
{
  const int tid  = threadIdx.x;
  const int wid  = tid >> 6;      // wave 0..3 : K-split (K = 1536 = 512 x + 1024 h)
  const int lane = tid & 63;
  const int quad = lane >> 4;
  const int lrow = lane & 15;

  const int wg   = blockIdx.x;
  const int gb   = wg >> 6;       // batch group 0..3
  const int gc   = wg & 63;       // col group 0..63
  const int b0   = gb << 4;
  const int col0 = gc << 4;

  const float* wi[4] = {wii, wif_, wig, wio};
  const float* wh[4] = {whi, whf, whg, who};
  const float* bi[4] = {bii, bif_, big_, bio};
  const float* bh[4] = {bhi, bhf, bhg, bho};

  uint32_t* zg = (uint32_t*)ws + gb * (2 * 16 * HH);  // this group's tagged-h buffers

  // ---- persistent weight fragments (B operand: B[k][n], n=lane&15, k=quad*8+j) ----
  const int kb = wid * 384;       // this wave's K-range in concatenated K=[x(512); h(1024)]
  half8 wfrag[12][4];
#pragma unroll
  for (int kk = 0; kk < 12; ++kk) {
    const int k = kb + kk * 32 + quad * 8;
#pragma unroll
    for (int g = 0; g < 4; ++g) {
      const float* wp = (k < II) ? (wi[g] + (size_t)(col0 + lrow) * II + k)
                                 : (wh[g] + (size_t)(col0 + lrow) * HH + (k - II));
      half8 v;
#pragma unroll
      for (int j = 0; j < 8; ++j) v[j] = (_Float16)wp[j];
      wfrag[kk][g] = v;
    }
  }

  // per-thread elementwise ownership: (tb, thc) = one (batch, h-col) cell
  const int tb   = tid >> 4;
  const int thc  = tid & 15;
  const int gcol = col0 + thc;
  float bias[4];
#pragma unroll
  for (int g = 0; g < 4; ++g) bias[g] = bi[g][gcol] + bh[g][gcol];

  float c = 0.0f, h = 0.0f;

  __shared__ float red[2][16 * 288];  // double-buffered -> no end-of-step barrier

#pragma unroll 1
  for (int t = 0; t < TT; ++t) {
    const uint32_t* zp   = zg + (t & 1) * (16 * HH);
    uint32_t*       zn   = zg + ((t + 1) & 1) * (16 * HH);
    const float*    xrow = x + ((size_t)t * BB + b0 + lrow) * II;
    const uint32_t* zrow = zp + lrow * HH;

    // A frags: A[m=lane&15][k=quad*8+j]; k<512 from x (L2-cached fp32)
    half8 af[12];
#pragma unroll
    for (int kk = 0; kk < 12; ++kk) {
      const int k = kb + kk * 32 + quad * 8;
      if (kb + kk * 32 < II) {
        f32x4 v0 = *(const f32x4*)(xrow + k);
        f32x4 v1 = *(const f32x4*)(xrow + k + 4);
        half8 v;
#pragma unroll
        for (int j = 0; j < 4; ++j) { v[j] = (_Float16)v0[j]; v[4 + j] = (_Float16)v1[j]; }
        af[kk] = v;
      }
    }

    // h-part: tag-polled loads. One-way latency: a word with the current tag IS the data.
    if (t == 0) {
#pragma unroll
      for (int kk = 0; kk < 12; ++kk)
        if (kb + kk * 32 >= II) {
          half8 v;
#pragma unroll
          for (int j = 0; j < 8; ++j) v[j] = (_Float16)0.0f;
          af[kk] = v;
        }
    } else {
      const uint32_t etag = 1u + ((t - 1) & 3u);
      int guard = 0;
      for (;;) {
        uint32_t bad = 0u;
#pragma unroll
        for (int kk = 0; kk < 12; ++kk) {
          const int k = kb + kk * 32 + quad * 8;
          if (kb + kk * 32 >= II) {
            const uint64_t* p = (const uint64_t*)(zrow + (k - II));
            union { uint64_t q[4]; uint32_t u[8]; } cv;
            cv.q[0] = __hip_atomic_load(p + 0, __ATOMIC_RELAXED, __HIP_MEMORY_SCOPE_AGENT);
            cv.q[1] = __hip_atomic_load(p + 1, __ATOMIC_RELAXED, __HIP_MEMORY_SCOPE_AGENT);
            cv.q[2] = __hip_atomic_load(p + 2, __ATOMIC_RELAXED, __HIP_MEMORY_SCOPE_AGENT);
            cv.q[3] = __hip_atomic_load(p + 3, __ATOMIC_RELAXED, __HIP_MEMORY_SCOPE_AGENT);
            half8 v;
#pragma unroll
            for (int j = 0; j < 8; ++j) {
              bad |= (cv.u[j] ^ etag) & 7u;
              v[j] = (_Float16)__uint_as_float(cv.u[j]);  // tag bits: <=2^-20 rel noise
            }
            af[kk] = v;
          }
        }
        if (__all(bad == 0u)) break;            // wave 0 has no h-frags -> exits instantly
        if (++guard > (1 << 18)) break;         // fail loud, not hang
        __builtin_amdgcn_s_sleep(2);
      }
    }

    f32x4 acc[4];
#pragma unroll
    for (int g = 0; g < 4; ++g) acc[g] = (f32x4){0.f, 0.f, 0.f, 0.f};
#pragma unroll
    for (int kk = 0; kk < 12; ++kk)
#pragma unroll
      for (int g = 0; g < 4; ++g)
        acc[g] = __builtin_amdgcn_mfma_f32_16x16x32_f16(af[kk], wfrag[kk][g], acc[g], 0, 0, 0);

    // cross-wave K reduction via LDS; D layout: row(m)=quad*4+r, col(n)=lane&15
    float* redb = red[t & 1];
#pragma unroll
    for (int g = 0; g < 4; ++g)
#pragma unroll
      for (int r = 0; r < 4; ++r)
        redb[(wid * 4 + g) * 288 + quad * 72 + r * 16 + lrow] = acc[g][r];
    __syncthreads();   // only barrier per step; all outstanding vmem is a step old

    float pre[4];
#pragma unroll
    for (int g = 0; g < 4; ++g) {
      float s = bias[g];
#pragma unroll
      for (int w = 0; w < 4; ++w)
        s += redb[(w * 4 + g) * 288 + (tb >> 2) * 72 + (tb & 3) * 16 + thc];
      pre[g] = s;
    }

    const float it = fsig(pre[0]);
    const float ft = fsig(pre[1]);
    const float gt = ftanh(pre[2]);
    const float ot = fsig(pre[3]);
    c = ft * c + it * gt;
    h = ot * ftanh(c);

    out[((size_t)t * BB + b0 + tb) * HH + gcol] = h;

    // publish: each thread fires ONE tagged word and moves on. No ack, no flag, no barrier.
    if (t < TT - 1) {
      const uint32_t stag = 1u + (t & 3u);
      __hip_atomic_store(zn + tb * HH + gcol, (__float_as_uint(h) & ~7u) | stag,
                         __ATOMIC_RELAXED, __HIP_MEMORY_SCOPE_AGENT);
    }
  }

  // tails: h_T then c_T, each [B][H]
  out[(size_t)TT * BB * HH + (size_t)(b0 + tb) * HH + gcol] = h;
  out[(size_t)TT * BB * HH + (size_t)BB * HH + (size_t)(b0 + tb) * HH + gcol] = c;
}

extern "C" void kernel_launch(void* const* d_in, const int* in_sizes, int n_in,
                              void* d_out, int out_size, void* d_ws, size_t ws_size,
                              hipStream_t stream) {
  const float* x    = (const float*)d_in[0];
  const float* wii  = (const float*)d_in[1];
  const float* bii  = (const float*)d_in[2];
  const float* wif_ = (const float*)d_in[3];
  const float* bif_ = (const float*)d_in[4];
  const float* wig  = (const float*)d_in[5];
  const float* big_ = (const float*)d_in[6];
  const float* wio  = (const float*)d_in[7];
  const float* bio  = (const float*)d_in[8];
  const float* whi  = (const float*)d_in[9];
  const float* bhi  = (const float*)d_in[10];
  const float* whf  = (const float*)d_in[11];
  const float* bhf  = (const float*)d_in[12];
  const float* whg  = (const float*)d_in[13];
  const float* bhg  = (const float*)d_in[14];
  const float* who  = (const float*)d_in[15];
  const float* bho  = (const float*)d_in[16];

  lstm_init<<<(ZWORDS + 255) / 256, 256, 0, stream>>>((uint32_t*)d_ws);
  lstm_persist<<<256, 256, 0, stream>>>(x, wii, bii, wif_, bif_, wig, big_, wio, bio,
                                        whi, bhi, whf, bhf, whg, bhg, who, bho,
                                        (float*)d_out, (uint8_t*)d_ws);
}

// Round 3
// 4239.043 us; speedup vs baseline: 4.0353x; 1.1101x over previous
//
#include <hip/hip_runtime.h>
#include <stdint.h>

#define TT 512
#define BB 64
#define II 512
#define HH 1024

typedef __attribute__((ext_vector_type(8))) _Float16 half8;
typedef __attribute__((ext_vector_type(4))) float f32x4;

__device__ __forceinline__ float fsig(float x)  { return 1.0f / (1.0f + __expf(-x)); }
__device__ __forceinline__ float ftanh(float x) { return 1.0f - 2.0f / (1.0f + __expf(2.0f * x)); }

// ws: 4 batch-groups x dbuf x [16][HH] f32 h words; low 3 bits of each word = step tag.
// tag(t) = 1 + (t & 3) in {1,2,3,4}; init 0 never matches; t vs t-2 tags always differ.
#define ZWORDS (4 * 2 * 16 * HH)

__global__ void lstm_init(uint32_t* ws) {
  const uint32_t i = blockIdx.x * 256u + threadIdx.x;
  if (i < ZWORDS) ws[i] = 0u;
}

// Persistent LSTM: 256 WGs = 4 batch-groups (16 batches) x 64 col-groups (16 h-cols x 4 gates).
// Weights live in VGPRs/AGPRs as fp16 MFMA B-frags. Cross-WG h exchange: self-validating
// tagged f32 words through L3 (relaxed agent atomics). Round-3 change: INCREMENTAL tag
// polling -- each lane keeps a pending-fragment mask and only re-loads stale frags, so
// steady-state poll traffic ~= one pass (16 MB/step device-wide) instead of ~4 passes.
__global__ __launch_bounds__(256, 1)
void lstm_persist(const float* __restrict__ x,
                  const float* __restrict__ wii, const float* __restrict__ bii,
                  const float* __restrict__ wif_, const float* __restrict__ bif_,
                  const float* __restrict__ wig, const float* __restrict__ big_,
                  const float* __restrict__ wio, const float* __restrict__ bio,
                  const float* __restrict__ whi, const float* __restrict__ bhi,
                  const float* __restrict__ whf, const float* __restrict__ bhf,
                  const float* __restrict__ whg, const float* __restrict__ bhg,
                  const float* __restrict__ who, const float* __restrict__ bho,
                  float* __restrict__ out, uint8_t* __restrict__ ws)
{
  const int tid  = threadIdx.x;
  const int wid  = tid >> 6;      // wave 0..3 : K-split (K = 1536 = 512 x + 1024 h)
  const int lane = tid & 63;
  const int quad = lane >> 4;
  const int lrow = lane & 15;

  const int wg   = blockIdx.x;
  const int gb   = wg >> 6;       // batch group 0..3
  const int gc   = wg & 63;       // col group 0..63
  const int b0   = gb << 4;
  const int col0 = gc << 4;

  const float* wi[4] = {wii, wif_, wig, wio};
  const float* wh[4] = {whi, whf, whg, who};
  const float* bi[4] = {bii, bif_, big_, bio};
  const float* bh[4] = {bhi, bhf, bhg, bho};

  uint32_t* zg = (uint32_t*)ws + gb * (2 * 16 * HH);  // this group's tagged-h buffers

  // ---- persistent weight fragments (B operand: B[k][n], n=lane&15, k=quad*8+j) ----
  const int kb = wid * 384;       // this wave's K-range in concatenated K=[x(512); h(1024)]
  half8 wfrag[12][4];
#pragma unroll
  for (int kk = 0; kk < 12; ++kk) {
    const int k = kb + kk * 32 + quad * 8;
#pragma unroll
    for (int g = 0; g < 4; ++g) {
      const float* wp = (k < II) ? (wi[g] + (size_t)(col0 + lrow) * II + k)
                                 : (wh[g] + (size_t)(col0 + lrow) * HH + (k - II));
      half8 v;
#pragma unroll
      for (int j = 0; j < 8; ++j) v[j] = (_Float16)wp[j];
      wfrag[kk][g] = v;
    }
  }

  // which kk slots are h-frags for this wave (wave-uniform)
  uint32_t hmask = 0u;
#pragma unroll
  for (int kk = 0; kk < 12; ++kk)
    if (kb + kk * 32 >= II) hmask |= 1u << kk;

  // per-thread elementwise ownership: (tb, thc) = one (batch, h-col) cell
  const int tb   = tid >> 4;
  const int thc  = tid & 15;
  const int gcol = col0 + thc;
  float bias[4];
#pragma unroll
  for (int g = 0; g < 4; ++g) bias[g] = bi[g][gcol] + bh[g][gcol];

  float c = 0.0f, h = 0.0f;

  __shared__ float red[2][16 * 288];  // double-buffered -> no end-of-step barrier

#pragma unroll 1
  for (int t = 0; t < TT; ++t) {
    const uint32_t* zp   = zg + (t & 1) * (16 * HH);
    uint32_t*       zn   = zg + ((t + 1) & 1) * (16 * HH);
    const float*    xrow = x + ((size_t)t * BB + b0 + lrow) * II;
    const uint32_t* zrow = zp + lrow * HH;

    // A frags: A[m=lane&15][k=quad*8+j]; k<512 from x (L2-cached fp32)
    half8 af[12];
#pragma unroll
    for (int kk = 0; kk < 12; ++kk) {
      const int k = kb + kk * 32 + quad * 8;
      if (kb + kk * 32 < II) {
        f32x4 v0 = *(const f32x4*)(xrow + k);
        f32x4 v1 = *(const f32x4*)(xrow + k + 4);
        half8 v;
#pragma unroll
        for (int j = 0; j < 4; ++j) { v[j] = (_Float16)v0[j]; v[4 + j] = (_Float16)v1[j]; }
        af[kk] = v;
      }
    }

    // h-part: incremental tag-polled loads. A word carrying the current tag IS the data;
    // lanes clear frags from `pend` as they turn fresh and only re-load the stale ones.
    if (t == 0) {
#pragma unroll
      for (int kk = 0; kk < 12; ++kk)
        if (kb + kk * 32 >= II) {
          half8 v;
#pragma unroll
          for (int j = 0; j < 8; ++j) v[j] = (_Float16)0.0f;
          af[kk] = v;
        }
    } else if (hmask) {
      const uint32_t etag = 1u + ((t - 1) & 3u);
      uint32_t pend = hmask;      // per-lane pending-fragment mask
      int guard = 0;
      for (;;) {
#pragma unroll
        for (int kk = 0; kk < 12; ++kk) {
          if (kb + kk * 32 < II) continue;           // wave-uniform skip
          if (pend & (1u << kk)) {                   // per-lane: only stale frags
            const int k = kb + kk * 32 + quad * 8;
            const uint64_t* p = (const uint64_t*)(zrow + (k - II));
            union { uint64_t q[4]; uint32_t u[8]; } cv;
            cv.q[0] = __hip_atomic_load(p + 0, __ATOMIC_RELAXED, __HIP_MEMORY_SCOPE_AGENT);
            cv.q[1] = __hip_atomic_load(p + 1, __ATOMIC_RELAXED, __HIP_MEMORY_SCOPE_AGENT);
            cv.q[2] = __hip_atomic_load(p + 2, __ATOMIC_RELAXED, __HIP_MEMORY_SCOPE_AGENT);
            cv.q[3] = __hip_atomic_load(p + 3, __ATOMIC_RELAXED, __HIP_MEMORY_SCOPE_AGENT);
            uint32_t bad = 0u;
#pragma unroll
            for (int j = 0; j < 8; ++j) bad |= (cv.u[j] ^ etag) & 7u;
            if (bad == 0u) {
              half8 v;
#pragma unroll
              for (int j = 0; j < 8; ++j)
                v[j] = (_Float16)__uint_as_float(cv.u[j]);  // tag bits: <=2^-20 rel noise
              af[kk] = v;
              pend &= ~(1u << kk);
            }
          }
        }
        if (__all(pend == 0u)) break;
        if (++guard > (1 << 18)) break;              // fail loud, not hang
        __builtin_amdgcn_s_sleep(1);
      }
    }

    f32x4 acc[4];
#pragma unroll
    for (int g = 0; g < 4; ++g) acc[g] = (f32x4){0.f, 0.f, 0.f, 0.f};
#pragma unroll
    for (int kk = 0; kk < 12; ++kk)
#pragma unroll
      for (int g = 0; g < 4; ++g)
        acc[g] = __builtin_amdgcn_mfma_f32_16x16x32_f16(af[kk], wfrag[kk][g], acc[g], 0, 0, 0);

    // cross-wave K reduction via LDS; D layout: row(m)=quad*4+r, col(n)=lane&15
    float* redb = red[t & 1];
#pragma unroll
    for (int g = 0; g < 4; ++g)
#pragma unroll
      for (int r = 0; r < 4; ++r)
        redb[(wid * 4 + g) * 288 + quad * 72 + r * 16 + lrow] = acc[g][r];
    __syncthreads();   // only barrier per step; all outstanding vmem is a step old

    float pre[4];
#pragma unroll
    for (int g = 0; g < 4; ++g) {
      float s = bias[g];
#pragma unroll
      for (int w = 0; w < 4; ++w)
        s += redb[(w * 4 + g) * 288 + (tb >> 2) * 72 + (tb & 3) * 16 + thc];
      pre[g] = s;
    }

    const float it = fsig(pre[0]);
    const float ft = fsig(pre[1]);
    const float gt = ftanh(pre[2]);
    const float ot = fsig(pre[3]);
    c = ft * c + it * gt;
    h = ot * ftanh(c);

    // publish FIRST (starts the one-way L3 trip earlier), then the HBM out-store.
    if (t < TT - 1) {
      const uint32_t stag = 1u + (t & 3u);
      __hip_atomic_store(zn + tb * HH + gcol, (__float_as_uint(h) & ~7u) | stag,
                         __ATOMIC_RELAXED, __HIP_MEMORY_SCOPE_AGENT);
    }
    out[((size_t)t * BB + b0 + tb) * HH + gcol] = h;
  }

  // tails: h_T then c_T, each [B][H]
  out[(size_t)TT * BB * HH + (size_t)(b0 + tb) * HH + gcol] = h;
  out[(size_t)TT * BB * HH + (size_t)BB * HH + (size_t)(b0 + tb) * HH + gcol] = c;
}

extern "C" void kernel_launch(void* const* d_in, const int* in_sizes, int n_in,
                              void* d_out, int out_size, void* d_ws, size_t ws_size,
                              hipStream_t stream) {
  const float* x    = (const float*)d_in[0];
  const float* wii  = (const float*)d_in[1];
  const float* bii  = (const float*)d_in[2];
  const float* wif_ = (const float*)d_in[3];
  const float* bif_ = (const float*)d_in[4];
  const float* wig  = (const float*)d_in[5];
  const float* big_ = (const float*)d_in[6];
  const float* wio  = (const float*)d_in[7];
  const float* bio  = (const float*)d_in[8];
  const float* whi  = (const float*)d_in[9];
  const float* bhi  = (const float*)d_in[10];
  const float* whf  = (const float*)d_in[11];
  const float* bhf  = (const float*)d_in[12];
  const float* whg  = (const float*)d_in[13];
  const float* bhg  = (const float*)d_in[14];
  const float* who  = (const float*)d_in[15];
  const float* bho  = (const float*)d_in[16];

  lstm_init<<<(ZWORDS + 255) / 256, 256, 0, stream>>>((uint32_t*)d_ws);
  lstm_persist<<<256, 256, 0, stream>>>(x, wii, bii, wif_, bif_, wig, big_, wio, bio,
                                        whi, bhi, whf, bhf, whg, bhg, who, bho,
                                        (float*)d_out, (uint8_t*)d_ws);
}